// Round 13
// baseline (30.590 us; speedup 1.0000x reference)
//
#include <hip/hip_runtime.h>

#define F 512
#define T 512
#define DEPTH 6
#define NL 64
#define NCOL 3072  // T*DEPTH

typedef __attribute__((ext_vector_type(8))) short short8v;
typedef __attribute__((ext_vector_type(4))) float float4v;

static __device__ __forceinline__ unsigned short f2bf(float f){
  unsigned u = __builtin_bit_cast(unsigned, f);
  unsigned r = (u + 0x7fffu + ((u >> 16) & 1u)) >> 16;  // RNE, finite values
  return (unsigned short)r;
}

// async global->LDS, 16B per lane; lds base must be wave-uniform (HW adds lane*16)
static __device__ __forceinline__ void glds16(const unsigned short* g, char* lds){
  __builtin_amdgcn_global_load_lds(
      (const __attribute__((address_space(1))) unsigned int*)(uintptr_t)(const void*)g,
      (__attribute__((address_space(3))) unsigned int*)(uintptr_t)(void*)lds,
      16, 0, 0);
}

// ------- kernel 1: x->bf16 + UNNORMALIZED exp(fa) transpose + colsums + resp pad -------
// grid (48, 8). partial[8][3072]. Softmax 1/S applied in k_main (GEMM linear in B).
// Also writes resp4[T][64][4] (float4-aligned response) for k_main's tree phase.
__global__ __launch_bounds__(256) void k_prep(const float* __restrict__ fa,
                                              const float* __restrict__ x,
                                              unsigned short* __restrict__ xb,
                                              unsigned short* __restrict__ cwT,
                                              float* __restrict__ partial,
                                              const float* __restrict__ resp,
                                              float* __restrict__ resp4){
  __shared__ float tile[64 * 65];
  __shared__ float red[4][64];
  int t = threadIdx.x, c = t & 63, q = t >> 6;
  int n0 = blockIdx.x * 64, k0 = blockIdx.y * 64;

  // x convert: 131072 float4 over 384 blocks x 256 thr (low gids take 2nd element)
  int gid = (blockIdx.y * 48 + blockIdx.x) * 256 + t;
  for (int i = gid; i < 131072; i += 98304){
    float4 v = ((const float4*)x)[i];
    ushort4 o;
    o.x = f2bf(v.x); o.y = f2bf(v.y); o.z = f2bf(v.z); o.w = f2bf(v.w);
    ((ushort4*)xb)[i] = o;
  }
  // response pad: 32768 leaf-slots (tree*64+leaf) handled by gids [65536, 98304)
  if (gid >= 65536){
    int i = gid - 65536;
    float4 o4;
    o4.x = resp[i * 3];
    o4.y = resp[i * 3 + 1];
    o4.z = resp[i * 3 + 2];
    o4.w = 0.f;
    ((float4*)resp4)[i] = o4;
  }

  // exp tile + per-thread column partials (exp computed ONCE, reused)
  float s = 0.f;
  #pragma unroll
  for (int i = 0; i < 16; ++i){
    int kk = q * 16 + i;
    float e = __expf(fa[(k0 + kk) * NCOL + n0 + c]);
    tile[c * 65 + kk] = e;
    s += e;
  }
  red[q][c] = s;
  __syncthreads();
  if (t < 64)
    partial[blockIdx.y * NCOL + n0 + t] = red[0][t] + red[1][t] + red[2][t] + red[3][t];

  // bf16 transpose write (unnormalized)
  #pragma unroll
  for (int j = 0; j < 2; ++j){
    int s2 = t + 256 * j;
    int nn = s2 >> 3, ko = s2 & 7;
    const float* tp = tile + nn * 65 + ko * 8;
    unsigned short tmp[8];
    #pragma unroll
    for (int z = 0; z < 8; ++z) tmp[z] = f2bf(tp[z]);
    *(int4*)(cwT + (n0 + nn) * F + k0 + ko * 8) = *(const int4*)tmp;
  }
}

// ------- kernel 2: glds + counted-vmcnt depth-1 MFMA GEMM + 1/S scale + tree -------
// Tile 64 b-rows x 16 trees (96 n). 256 thr / 4 waves (2m x 2n). Grid 512 (XCD-swizzled).
// LDS: A dbuf 2x[64][128B] @0/@8192, B dbuf 2x[96][128B] @16384/@28672 (linear,
// content swizzled: LDS[row][b] = src[row][b ^ ((row&7)<<4)]), sL @40960.
// Total 41.3KB -> 3 blocks/CU. Tree reads response from global resp4 (L1-resident).
// fvl [64][100] f32 overlays A/B after GEMM.
#define AB0 0
#define AB1 8192
#define BB0 16384
#define BB1 28672
#define SL_OFF 40960
#define SMEM3 (40960 + 384)
__global__ __launch_bounds__(256) void k_main(
    const unsigned short* __restrict__ xb, const unsigned short* __restrict__ cwT,
    const float* __restrict__ thr, const float* __restrict__ ltm,
    const float* __restrict__ resp4, const float* __restrict__ partial,
    float* __restrict__ out){
  __shared__ char smem[SMEM3];
  float* fvl = (float*)smem;                 // [64][100] f32 (post-GEMM overlay)
  float* sL  = (float*)(smem + SL_OFF);      // [96] inv column sums

  int t = threadIdx.x;
  // bijective XCD-chunked swizzle (512 % 8 == 0): each XCD owns 4 whole ty-panels
  int wg = blockIdx.x;
  int sid = (wg & 7) * 64 + (wg >> 3);
  int bx = sid & 15, ty = sid >> 4;
  int b0 = bx * 64;
  int t0 = ty * 16, n0 = ty * 96;

  // wave/lane decomposition
  int w = t >> 6, l = t & 63;
  int wm = w >> 1, wn = w & 1;
  int lr = l & 15, lg = l >> 4;
  int lrow8 = l >> 3;                          // 0..7
  int lswz = ((l & 7) ^ lrow8) << 3;           // inverse-swizzle elem offset in row

  // staging sources (per-lane, constant rows; only k advances)
  const unsigned short* gA0 = xb  + (b0 + w * 16 + 0 + lrow8) * F + lswz;
  const unsigned short* gA1 = xb  + (b0 + w * 16 + 8 + lrow8) * F + lswz;
  const unsigned short* gB0 = cwT + (n0 + w * 24 + 0 + lrow8) * F + lswz;
  const unsigned short* gB1 = cwT + (n0 + w * 24 + 8 + lrow8) * F + lswz;
  const unsigned short* gB2 = cwT + (n0 + w * 24 + 16 + lrow8) * F + lswz;
  // wave-uniform LDS dest offsets
  int lA = w * 16 * 128;
  int lB = w * 24 * 128;

  // prologue: stage chunk 0 into buf 0 FIRST (latency hides under sL setup)
  glds16(gA0, smem + AB0 + lA);
  glds16(gA1, smem + AB0 + lA + 1024);
  glds16(gB0, smem + BB0 + lB);
  glds16(gB1, smem + BB0 + lB + 1024);
  glds16(gB2, smem + BB0 + lB + 2048);

  // inv softmax denominators for this block's 96 columns
  if (t < 96){
    float s = 0.f;
    #pragma unroll
    for (int i = 0; i < 8; ++i) s += partial[i * NCOL + n0 + t];
    sL[t] = 1.0f / s;
  }

  float4v acc[2][3];
  #pragma unroll
  for (int i = 0; i < 2; ++i)
    #pragma unroll
    for (int j = 0; j < 3; ++j) acc[i][j] = (float4v){0.f,0.f,0.f,0.f};

  __syncthreads();   // chunk-0 staged (drains vmcnt) + sL visible

  int swz = (lr & 7) << 4;
  #pragma unroll
  for (int cc = 0; cc < 8; ++cc){
    char* Ab = smem + ((cc & 1) ? AB1 : AB0);
    char* Bb = smem + ((cc & 1) ? BB1 : BB0);
    // issue next chunk's async stages into buf^1 (fly across the barrier; T4)
    if (cc < 7){
      int kc = (cc + 1) * 64;
      char* An = smem + ((cc & 1) ? AB0 : AB1);
      char* Bn = smem + ((cc & 1) ? BB0 : BB1);
      glds16(gA0 + kc, An + lA);
      glds16(gA1 + kc, An + lA + 1024);
      glds16(gB0 + kc, Bn + lB);
      glds16(gB1 + kc, Bn + lB + 1024);
      glds16(gB2 + kc, Bn + lB + 2048);
    }
    // wait ONLY the oldest 5 loads (current chunk); next chunk's stay in flight
    if (cc < 7) asm volatile("s_waitcnt vmcnt(5)" ::: "memory");
    else        asm volatile("s_waitcnt vmcnt(0)" ::: "memory");
    asm volatile("s_barrier" ::: "memory");   // all waves' chunk-cc rows landed
    // compute chunk cc (swizzled fragment reads, 2-way banks = free)
    char* Ar = Ab + (wm * 32 + lr) * 128;
    char* Br = Bb + (wn * 48 + lr) * 128;
    #pragma unroll
    for (int ks = 0; ks < 2; ++ks){
      int ko = (ks * 64 + lg * 16) ^ swz;
      short8v a0 = *(const short8v*)(Ar + ko);
      short8v a1 = *(const short8v*)(Ar + 2048 + ko);
      short8v b0 = *(const short8v*)(Br + ko);
      short8v b1 = *(const short8v*)(Br + 2048 + ko);
      short8v b2 = *(const short8v*)(Br + 4096 + ko);
      acc[0][0] = __builtin_amdgcn_mfma_f32_16x16x32_bf16(a0, b0, acc[0][0], 0, 0, 0);
      acc[0][1] = __builtin_amdgcn_mfma_f32_16x16x32_bf16(a0, b1, acc[0][1], 0, 0, 0);
      acc[0][2] = __builtin_amdgcn_mfma_f32_16x16x32_bf16(a0, b2, acc[0][2], 0, 0, 0);
      acc[1][0] = __builtin_amdgcn_mfma_f32_16x16x32_bf16(a1, b0, acc[1][0], 0, 0, 0);
      acc[1][1] = __builtin_amdgcn_mfma_f32_16x16x32_bf16(a1, b1, acc[1][1], 0, 0, 0);
      acc[1][2] = __builtin_amdgcn_mfma_f32_16x16x32_bf16(a1, b2, acc[1][2], 0, 0, 0);
    }
    // readers done before next iter's glds overwrites this buffer
    asm volatile("s_barrier" ::: "memory");
  }

  // spill fv with 1/S scaling: C/D layout col=lane&15, row=(lane>>4)*4+reg
  // (loop's final barrier guarantees all waves finished reading A/B LDS)
  float sf0 = sL[wn * 48 + lr];
  float sf1 = sL[wn * 48 + 16 + lr];
  float sf2 = sL[wn * 48 + 32 + lr];
  #pragma unroll
  for (int fm = 0; fm < 2; ++fm)
    #pragma unroll
    for (int r = 0; r < 4; ++r){
      int m = wm * 32 + fm * 16 + lg * 4 + r;
      fvl[m * 100 + wn * 48 + lr]      = acc[fm][0][r] * sf0;
      fvl[m * 100 + wn * 48 + 16 + lr] = acc[fm][1][r] * sf1;
      fvl[m * 100 + wn * 48 + 32 + lr] = acc[fm][2][r] * sf2;
    }
  __syncthreads();

  // ---- tree phase: thread owns tree tl for 4 rows bl0+16p ----
  int tl = t & 15, bl0 = t >> 4;
  const float* thp = thr + (t0 + tl) * 6;
  const float* ltp = ltm + (t0 + tl) * 6;
  float av[DEPTH], cv[DEPTH];
  #pragma unroll
  for (int d = 0; d < DEPTH; ++d){
    av[d] = 0.5f * __expf(-ltp[d]);
    cv[d] = 0.5f - thp[d] * av[d];
  }
  float wv[4][16], qq[4][4];
  #pragma unroll
  for (int p = 0; p < 4; ++p){
    int bl = bl0 + 16 * p;
    float bn[DEPTH];
    #pragma unroll
    for (int d = 0; d < DEPTH; ++d)
      bn[d] = fminf(fmaxf(fvl[bl * 100 + tl * 6 + d] * av[d] + cv[d], 0.0f), 1.0f);
    wv[p][0] = bn[0]; wv[p][1] = 1.0f - bn[0];
    #pragma unroll
    for (int j = 1; j < 4; ++j){
      int half = 1 << j;
      float g = bn[j];
      #pragma unroll
      for (int i = 0; i < half; ++i){
        float o = wv[p][i];
        wv[p][i] = o * g;
        wv[p][i + half] = o - wv[p][i];   // o*(1-g)
      }
    }
    // quadrant multipliers: leaf = i + 16*bit4 + 32*bit5; bit set -> (1-bn)
    float p4 = bn[4], p5 = bn[5];
    qq[p][0] = p4 * p5;
    qq[p][1] = (1.0f - p4) * p5;
    qq[p][2] = p4 * (1.0f - p5);
    qq[p][3] = (1.0f - p4) * (1.0f - p5);
  }
  float4v oa[4];
  #pragma unroll
  for (int p = 0; p < 4; ++p) oa[p] = (float4v){0.f,0.f,0.f,0.f};
  const float4v* rq = (const float4v*)(resp4 + (t0 + tl) * (NL * 4));
  #pragma unroll
  for (int i = 0; i < 16; ++i){
    float4v r0  = rq[i];
    float4v r16 = rq[i + 16];
    float4v r32 = rq[i + 32];
    float4v r48 = rq[i + 48];
    #pragma unroll
    for (int p = 0; p < 4; ++p){
      float4v s = r0 * qq[p][0] + r16 * qq[p][1] + r32 * qq[p][2] + r48 * qq[p][3];
      oa[p] += s * wv[p][i];
    }
  }
  #pragma unroll
  for (int p = 0; p < 4; ++p){
    float* op = out + (b0 + bl0 + 16 * p) * (T * 3) + (t0 + tl) * 3;
    op[0] = oa[p][0]; op[1] = oa[p][1]; op[2] = oa[p][2];
  }
}

extern "C" void kernel_launch(void* const* d_in, const int* in_sizes, int n_in,
                              void* d_out, int out_size, void* d_ws, size_t ws_size,
                              hipStream_t stream){
  const float* x    = (const float*)d_in[0];
  const float* fa   = (const float*)d_in[1];
  const float* thr  = (const float*)d_in[2];
  const float* ltm  = (const float*)d_in[3];
  const float* resp = (const float*)d_in[4];
  float* out = (float*)d_out;

  unsigned short* cwT = (unsigned short*)d_ws;                      // @0, 3 MB
  unsigned short* xb  = (unsigned short*)((char*)d_ws + (3 << 20)); // @3MB, 1 MB
  float* partial      = (float*)((char*)d_ws + (4 << 20));          // @4MB, 96 KB
  float* resp4        = (float*)((char*)d_ws + (5 << 20));          // @5MB, 512 KB

  k_prep<<<dim3(48, 8), 256, 0, stream>>>(fa, x, xb, cwT, partial, resp, resp4);
  k_main<<<512, 256, 0, stream>>>(xb, cwT, thr, ltm, resp4, partial, out);
}

// Round 14
// 21.076 us; speedup vs baseline: 1.4514x; 1.4514x over previous
//
#include <hip/hip_runtime.h>

#define F 512
#define T 512
#define DEPTH 6
#define NL 64
#define NCOL 3072  // T*DEPTH

typedef __attribute__((ext_vector_type(8))) short short8v;
typedef __attribute__((ext_vector_type(4))) float float4v;

static __device__ __forceinline__ unsigned short f2bf(float f){
  unsigned u = __builtin_bit_cast(unsigned, f);
  unsigned r = (u + 0x7fffu + ((u >> 16) & 1u)) >> 16;  // RNE, finite values
  return (unsigned short)r;
}

// async global->LDS, 16B per lane; lds base must be wave-uniform (HW adds lane*16)
static __device__ __forceinline__ void glds16(const unsigned short* g, char* lds){
  __builtin_amdgcn_global_load_lds(
      (const __attribute__((address_space(1))) unsigned int*)(uintptr_t)(const void*)g,
      (__attribute__((address_space(3))) unsigned int*)(uintptr_t)(void*)lds,
      16, 0, 0);
}

// ------- kernel 1: x->bf16 + UNNORMALIZED exp(fa) transpose + column partial sums -------
// grid (48, 8). partial[8][3072]. Softmax 1/S applied in k_main (GEMM linear in B).
__global__ __launch_bounds__(256) void k_prep(const float* __restrict__ fa,
                                              const float* __restrict__ x,
                                              unsigned short* __restrict__ xb,
                                              unsigned short* __restrict__ cwT,
                                              float* __restrict__ partial){
  __shared__ float tile[64 * 65];
  __shared__ float red[4][64];
  int t = threadIdx.x, c = t & 63, q = t >> 6;
  int n0 = blockIdx.x * 64, k0 = blockIdx.y * 64;

  // x convert: 131072 float4 over 384 blocks x 256 thr
  int gid = (blockIdx.y * 48 + blockIdx.x) * 256 + t;
  for (int i = gid; i < 131072; i += 98304){
    float4 v = ((const float4*)x)[i];
    ushort4 o;
    o.x = f2bf(v.x); o.y = f2bf(v.y); o.z = f2bf(v.z); o.w = f2bf(v.w);
    ((ushort4*)xb)[i] = o;
  }

  // exp tile + per-thread column partials (exp computed ONCE, reused)
  float s = 0.f;
  #pragma unroll
  for (int i = 0; i < 16; ++i){
    int kk = q * 16 + i;
    float e = __expf(fa[(k0 + kk) * NCOL + n0 + c]);
    tile[c * 65 + kk] = e;
    s += e;
  }
  red[q][c] = s;
  __syncthreads();
  if (t < 64)
    partial[blockIdx.y * NCOL + n0 + t] = red[0][t] + red[1][t] + red[2][t] + red[3][t];

  // bf16 transpose write (unnormalized)
  #pragma unroll
  for (int j = 0; j < 2; ++j){
    int s2 = t + 256 * j;
    int nn = s2 >> 3, ko = s2 & 7;
    const float* tp = tile + nn * 65 + ko * 8;
    unsigned short tmp[8];
    #pragma unroll
    for (int z = 0; z < 8; ++z) tmp[z] = f2bf(tp[z]);
    *(int4*)(cwT + (n0 + nn) * F + k0 + ko * 8) = *(const int4*)tmp;
  }
}

// ------- kernel 2: 128-row tile, 8-wave, glds + counted-vmcnt depth-1 GEMM + tree -------
// Tile 128 b-rows x 16 trees (96 n). 512 thr / 8 waves (4m x 2n). Grid 256 (XCD-swizzled).
// LDS: A dbuf 2x[128][128B] @0/@16384, B dbuf 2x[96][128B] @32768/@45056 (linear,
// content swizzled: LDS[row][b] = src[row][b ^ ((row&7)<<4)]), sL @57344, rsp @57728.
// fvl [128][100] f32 (51.2KB) overlays A/B after GEMM. Total 74.4KB -> 2 blocks/CU.
#define AB0 0
#define AB1 16384
#define BB0 32768
#define BB1 45056
#define SL_OFF 57344
#define RSP_OFF 57728
#define RSP_STRIDE 260
#define SMEM3 (57728 + 16640)
__global__ __launch_bounds__(512) void k_main(
    const unsigned short* __restrict__ xb, const unsigned short* __restrict__ cwT,
    const float* __restrict__ thr, const float* __restrict__ ltm,
    const float* __restrict__ resp, const float* __restrict__ partial,
    float* __restrict__ out){
  __shared__ char smem[SMEM3];
  float* fvl = (float*)smem;                 // [128][100] f32 (post-GEMM overlay)
  float* sL  = (float*)(smem + SL_OFF);      // [96] inv column sums
  float* rsp = (float*)(smem + RSP_OFF);     // [16][RSP_STRIDE] f32

  int t = threadIdx.x;
  // bijective XCD-chunked swizzle (256 % 8 == 0): each XCD owns 4 whole ty-panels
  int wg = blockIdx.x;
  int sid = (wg & 7) * 32 + (wg >> 3);
  int bx = sid & 7, ty = sid >> 3;
  int b0 = bx * 128;
  int t0 = ty * 16, n0 = ty * 96;

  // wave/lane decomposition (8 waves: 4m x 2n)
  int w = t >> 6, l = t & 63;
  int wm = w >> 1, wn = w & 1;
  int lr = l & 15, lg = l >> 4;
  int lrow8 = l >> 3;                          // 0..7
  int lswz = ((l & 7) ^ lrow8) << 3;           // inverse-swizzle elem offset in row

  // staging sources (per-lane, constant rows; only k advances)
  // A: wave w stages rows [16w, 16w+16) of the 128-row tile (2 glds)
  const unsigned short* gA = xb + (b0 + w * 16 + lrow8) * F + lswz;
  // B: waves 0..3 stage rows [16w,16w+16) (2 glds); waves 4..7 rows [64+8(w-4),+8) (1)
  int bB = (w < 4) ? (w * 16) : (64 + 8 * (w - 4));
  const unsigned short* gB = cwT + (n0 + bB + lrow8) * F + lswz;
  // wave-uniform LDS dest offsets
  int lA = w * 16 * 128;
  int lB = bB * 128;

  // prologue: stage chunk 0 into buf 0 FIRST (latency hides under sL/rsp setup)
  glds16(gA, smem + AB0 + lA);
  glds16(gA + 8 * F, smem + AB0 + lA + 1024);
  glds16(gB, smem + BB0 + lB);
  if (w < 4) glds16(gB + 8 * F, smem + BB0 + lB + 1024);

  // inv softmax denominators for this block's 96 columns
  if (t < 96){
    float s = 0.f;
    #pragma unroll
    for (int i = 0; i < 8; ++i) s += partial[i * NCOL + n0 + t];
    sL[t] = 1.0f / s;
  }
  // stage response: [16 trees][leaf*4+comp] padded float4 slots (768 slots, 512 thr)
  {
    const float4* rg = (const float4*)(resp + t0 * (NL * 3));
    #pragma unroll
    for (int j = 0; j < 2; ++j){
      int s = t + 512 * j;
      if (s < 768){
        int tr = s / 48, m0 = (s % 48) * 4;
        float4 v = rg[s];
        float vv[4] = {v.x, v.y, v.z, v.w};
        #pragma unroll
        for (int z = 0; z < 4; ++z){
          int m = m0 + z;
          rsp[tr * RSP_STRIDE + (m / 3) * 4 + (m % 3)] = vv[z];
        }
      }
    }
  }

  float4v acc[2][3];
  #pragma unroll
  for (int i = 0; i < 2; ++i)
    #pragma unroll
    for (int j = 0; j < 3; ++j) acc[i][j] = (float4v){0.f,0.f,0.f,0.f};

  __syncthreads();   // chunk-0 staged (drains vmcnt) + sL/rsp visible

  int swz = (lr & 7) << 4;
  #pragma unroll
  for (int cc = 0; cc < 8; ++cc){
    char* Ab = smem + ((cc & 1) ? AB1 : AB0);
    char* Bb = smem + ((cc & 1) ? BB1 : BB0);
    // issue next chunk's async stages into buf^1 (fly across the barrier; T4)
    if (cc < 7){
      int kc = (cc + 1) * 64;
      char* An = smem + ((cc & 1) ? AB0 : AB1);
      char* Bn = smem + ((cc & 1) ? BB0 : BB1);
      glds16(gA + kc, An + lA);
      glds16(gA + kc + 8 * F, An + lA + 1024);
      glds16(gB + kc, Bn + lB);
      if (w < 4) glds16(gB + kc + 8 * F, Bn + lB + 1024);
    }
    // wait ONLY the current chunk's loads (per-wave counted; next chunk stays in flight)
    if (cc < 7){
      if (w < 4) asm volatile("s_waitcnt vmcnt(4)" ::: "memory");
      else       asm volatile("s_waitcnt vmcnt(3)" ::: "memory");
    } else {
      asm volatile("s_waitcnt vmcnt(0)" ::: "memory");
    }
    asm volatile("s_barrier" ::: "memory");   // all waves' chunk-cc rows landed
    // compute chunk cc (swizzled fragment reads, 2-way banks = free)
    char* Ar = Ab + (wm * 32 + lr) * 128;
    char* Br = Bb + (wn * 48 + lr) * 128;
    #pragma unroll
    for (int ks = 0; ks < 2; ++ks){
      int ko = (ks * 64 + lg * 16) ^ swz;
      short8v a0 = *(const short8v*)(Ar + ko);
      short8v a1 = *(const short8v*)(Ar + 2048 + ko);
      short8v b0 = *(const short8v*)(Br + ko);
      short8v b1 = *(const short8v*)(Br + 2048 + ko);
      short8v b2 = *(const short8v*)(Br + 4096 + ko);
      acc[0][0] = __builtin_amdgcn_mfma_f32_16x16x32_bf16(a0, b0, acc[0][0], 0, 0, 0);
      acc[0][1] = __builtin_amdgcn_mfma_f32_16x16x32_bf16(a0, b1, acc[0][1], 0, 0, 0);
      acc[0][2] = __builtin_amdgcn_mfma_f32_16x16x32_bf16(a0, b2, acc[0][2], 0, 0, 0);
      acc[1][0] = __builtin_amdgcn_mfma_f32_16x16x32_bf16(a1, b0, acc[1][0], 0, 0, 0);
      acc[1][1] = __builtin_amdgcn_mfma_f32_16x16x32_bf16(a1, b1, acc[1][1], 0, 0, 0);
      acc[1][2] = __builtin_amdgcn_mfma_f32_16x16x32_bf16(a1, b2, acc[1][2], 0, 0, 0);
    }
    // readers done before next iter's glds overwrites this buffer
    asm volatile("s_barrier" ::: "memory");
  }

  // spill fv with 1/S scaling: C/D layout col=lane&15, row=(lane>>4)*4+reg
  float sf0 = sL[wn * 48 + lr];
  float sf1 = sL[wn * 48 + 16 + lr];
  float sf2 = sL[wn * 48 + 32 + lr];
  #pragma unroll
  for (int fm = 0; fm < 2; ++fm)
    #pragma unroll
    for (int r = 0; r < 4; ++r){
      int m = wm * 32 + fm * 16 + lg * 4 + r;
      fvl[m * 100 + wn * 48 + lr]      = acc[fm][0][r] * sf0;
      fvl[m * 100 + wn * 48 + 16 + lr] = acc[fm][1][r] * sf1;
      fvl[m * 100 + wn * 48 + 32 + lr] = acc[fm][2][r] * sf2;
    }
  __syncthreads();

  // ---- tree phase: thread owns tree tl for 4 rows bl0+32p ----
  int tl = t & 15, bl0 = t >> 4;     // bl0 in 0..31
  const float* thp = thr + (t0 + tl) * 6;
  const float* ltp = ltm + (t0 + tl) * 6;
  float av[DEPTH], cv[DEPTH];
  #pragma unroll
  for (int d = 0; d < DEPTH; ++d){
    av[d] = 0.5f * __expf(-ltp[d]);
    cv[d] = 0.5f - thp[d] * av[d];
  }
  float wv[4][16], qq[4][4];
  #pragma unroll
  for (int p = 0; p < 4; ++p){
    int bl = bl0 + 32 * p;
    float bn[DEPTH];
    #pragma unroll
    for (int d = 0; d < DEPTH; ++d)
      bn[d] = fminf(fmaxf(fvl[bl * 100 + tl * 6 + d] * av[d] + cv[d], 0.0f), 1.0f);
    wv[p][0] = bn[0]; wv[p][1] = 1.0f - bn[0];
    #pragma unroll
    for (int j = 1; j < 4; ++j){
      int half = 1 << j;
      float g = bn[j];
      #pragma unroll
      for (int i = 0; i < half; ++i){
        float o = wv[p][i];
        wv[p][i] = o * g;
        wv[p][i + half] = o - wv[p][i];   // o*(1-g)
      }
    }
    // quadrant multipliers: leaf = i + 16*bit4 + 32*bit5; bit set -> (1-bn)
    float p4 = bn[4], p5 = bn[5];
    qq[p][0] = p4 * p5;
    qq[p][1] = (1.0f - p4) * p5;
    qq[p][2] = p4 * (1.0f - p5);
    qq[p][3] = (1.0f - p4) * (1.0f - p5);
  }
  float4v oa[4];
  #pragma unroll
  for (int p = 0; p < 4; ++p) oa[p] = (float4v){0.f,0.f,0.f,0.f};
  const float* rp = rsp + tl * RSP_STRIDE;
  #pragma unroll
  for (int i = 0; i < 16; ++i){
    float4v r0  = *(const float4v*)(rp + i * 4);
    float4v r16 = *(const float4v*)(rp + (i + 16) * 4);
    float4v r32 = *(const float4v*)(rp + (i + 32) * 4);
    float4v r48 = *(const float4v*)(rp + (i + 48) * 4);
    #pragma unroll
    for (int p = 0; p < 4; ++p){
      float4v s = r0 * qq[p][0] + r16 * qq[p][1] + r32 * qq[p][2] + r48 * qq[p][3];
      oa[p] += s * wv[p][i];
    }
  }
  #pragma unroll
  for (int p = 0; p < 4; ++p){
    float* op = out + (b0 + bl0 + 32 * p) * (T * 3) + (t0 + tl) * 3;
    op[0] = oa[p][0]; op[1] = oa[p][1]; op[2] = oa[p][2];
  }
}

extern "C" void kernel_launch(void* const* d_in, const int* in_sizes, int n_in,
                              void* d_out, int out_size, void* d_ws, size_t ws_size,
                              hipStream_t stream){
  const float* x    = (const float*)d_in[0];
  const float* fa   = (const float*)d_in[1];
  const float* thr  = (const float*)d_in[2];
  const float* ltm  = (const float*)d_in[3];
  const float* resp = (const float*)d_in[4];
  float* out = (float*)d_out;

  unsigned short* cwT = (unsigned short*)d_ws;                      // @0, 3 MB
  unsigned short* xb  = (unsigned short*)((char*)d_ws + (3 << 20)); // @3MB, 1 MB
  float* partial      = (float*)((char*)d_ws + (4 << 20));          // @4MB, 96 KB

  k_prep<<<dim3(48, 8), 256, 0, stream>>>(fa, x, xb, cwT, partial);
  k_main<<<256, 512, 0, stream>>>(xb, cwT, thr, ltm, resp, partial, out);
}

// Round 15
// 20.543 us; speedup vs baseline: 1.4891x; 1.0260x over previous
//
#include <hip/hip_runtime.h>

#define F 512
#define T 512
#define DEPTH 6
#define NL 64
#define NCOL 3072  // T*DEPTH

typedef __attribute__((ext_vector_type(8))) short short8v;
typedef __attribute__((ext_vector_type(4))) float float4v;

static __device__ __forceinline__ unsigned short f2bf(float f){
  unsigned u = __builtin_bit_cast(unsigned, f);
  unsigned r = (u + 0x7fffu + ((u >> 16) & 1u)) >> 16;  // RNE, finite values
  return (unsigned short)r;
}

// async global->LDS, 16B per lane; lds base must be wave-uniform (HW adds lane*16)
static __device__ __forceinline__ void glds16(const unsigned short* g, char* lds){
  __builtin_amdgcn_global_load_lds(
      (const __attribute__((address_space(1))) unsigned int*)(uintptr_t)(const void*)g,
      (__attribute__((address_space(3))) unsigned int*)(uintptr_t)(void*)lds,
      16, 0, 0);
}

// ------- kernel 1: x->bf16 + UNNORMALIZED exp(fa) transpose + column partial sums -------
// grid (48, 16) = 768 blocks = exactly 3/CU (load-balanced). Each: 64 cols x 32 rows.
// partial[16][3072]. Softmax 1/S applied in k_main (GEMM linear in B).
__global__ __launch_bounds__(256) void k_prep(const float* __restrict__ fa,
                                              const float* __restrict__ x,
                                              unsigned short* __restrict__ xb,
                                              unsigned short* __restrict__ cwT,
                                              float* __restrict__ partial){
  __shared__ float tile[64 * 33];
  __shared__ float red[4][64];
  int t = threadIdx.x, c = t & 63, q = t >> 6;
  int n0 = blockIdx.x * 64, k0 = blockIdx.y * 32;

  // x convert: 131072 float4 over 768 blocks x 256 thr (<=1 per thread)
  int gid = (blockIdx.y * 48 + blockIdx.x) * 256 + t;
  if (gid < 131072){
    float4 v = ((const float4*)x)[gid];
    ushort4 o;
    o.x = f2bf(v.x); o.y = f2bf(v.y); o.z = f2bf(v.z); o.w = f2bf(v.w);
    ((ushort4*)xb)[gid] = o;
  }

  // exp tile + per-thread column partials (exp computed ONCE, reused)
  float s = 0.f;
  #pragma unroll
  for (int i = 0; i < 8; ++i){
    int kk = q * 8 + i;
    float e = __expf(fa[(k0 + kk) * NCOL + n0 + c]);
    tile[c * 33 + kk] = e;
    s += e;
  }
  red[q][c] = s;
  __syncthreads();
  if (t < 64)
    partial[blockIdx.y * NCOL + n0 + t] = red[0][t] + red[1][t] + red[2][t] + red[3][t];

  // bf16 transpose write (unnormalized): 64 n x 4 k-segments = 256 slots
  {
    int nn = t >> 2, ko = t & 3;
    const float* tp = tile + nn * 33 + ko * 8;
    unsigned short tmp[8];
    #pragma unroll
    for (int z = 0; z < 8; ++z) tmp[z] = f2bf(tp[z]);
    *(int4*)(cwT + (n0 + nn) * F + k0 + ko * 8) = *(const int4*)tmp;
  }
}

// ------- kernel 2: 128-row tile, 8-wave, glds + counted-vmcnt depth-1 GEMM + tree -------
// Tile 128 b-rows x 16 trees (96 n). 512 thr / 8 waves (4m x 2n). Grid 256 (XCD-swizzled).
// LDS: A dbuf 2x[128][128B] @0/@16384, B dbuf 2x[96][128B] @32768/@45056 (linear,
// content swizzled: LDS[row][b] = src[row][b ^ ((row&7)<<4)]), sL @57344, rsp @57728.
// fvl [128][100] f32 (51.2KB) overlays A/B after GEMM. Total 74.4KB -> 2 blocks/CU.
#define AB0 0
#define AB1 16384
#define BB0 32768
#define BB1 45056
#define SL_OFF 57344
#define RSP_OFF 57728
#define RSP_STRIDE 260
#define SMEM3 (57728 + 16640)
__global__ __launch_bounds__(512) void k_main(
    const unsigned short* __restrict__ xb, const unsigned short* __restrict__ cwT,
    const float* __restrict__ thr, const float* __restrict__ ltm,
    const float* __restrict__ resp, const float* __restrict__ partial,
    float* __restrict__ out){
  __shared__ char smem[SMEM3];
  float* fvl = (float*)smem;                 // [128][100] f32 (post-GEMM overlay)
  float* sL  = (float*)(smem + SL_OFF);      // [96] inv column sums
  float* rsp = (float*)(smem + RSP_OFF);     // [16][RSP_STRIDE] f32

  int t = threadIdx.x;
  // bijective XCD-chunked swizzle (256 % 8 == 0): each XCD owns 4 whole ty-panels
  int wg = blockIdx.x;
  int sid = (wg & 7) * 32 + (wg >> 3);
  int bx = sid & 7, ty = sid >> 3;
  int b0 = bx * 128;
  int t0 = ty * 16, n0 = ty * 96;

  // wave/lane decomposition (8 waves: 4m x 2n)
  int w = t >> 6, l = t & 63;
  int wm = w >> 1, wn = w & 1;
  int lr = l & 15, lg = l >> 4;
  int lrow8 = l >> 3;                          // 0..7
  int lswz = ((l & 7) ^ lrow8) << 3;           // inverse-swizzle elem offset in row

  // staging sources (per-lane, constant rows; only k advances)
  // A: wave w stages rows [16w, 16w+16) of the 128-row tile (2 glds)
  const unsigned short* gA = xb + (b0 + w * 16 + lrow8) * F + lswz;
  // B: waves 0..3 stage rows [16w,16w+16) (2 glds); waves 4..7 rows [64+8(w-4),+8) (1)
  int bB = (w < 4) ? (w * 16) : (64 + 8 * (w - 4));
  const unsigned short* gB = cwT + (n0 + bB + lrow8) * F + lswz;
  // wave-uniform LDS dest offsets
  int lA = w * 16 * 128;
  int lB = bB * 128;

  // prologue: stage chunk 0 into buf 0 FIRST (latency hides under sL/rsp setup)
  glds16(gA, smem + AB0 + lA);
  glds16(gA + 8 * F, smem + AB0 + lA + 1024);
  glds16(gB, smem + BB0 + lB);
  if (w < 4) glds16(gB + 8 * F, smem + BB0 + lB + 1024);

  // inv softmax denominators for this block's 96 columns (16 k-slabs now)
  if (t < 96){
    float s = 0.f;
    #pragma unroll
    for (int i = 0; i < 16; ++i) s += partial[i * NCOL + n0 + t];
    sL[t] = 1.0f / s;
  }
  // stage response: [16 trees][leaf*4+comp] padded float4 slots (768 slots, 512 thr)
  {
    const float4* rg = (const float4*)(resp + t0 * (NL * 3));
    #pragma unroll
    for (int j = 0; j < 2; ++j){
      int s = t + 512 * j;
      if (s < 768){
        int tr = s / 48, m0 = (s % 48) * 4;
        float4 v = rg[s];
        float vv[4] = {v.x, v.y, v.z, v.w};
        #pragma unroll
        for (int z = 0; z < 4; ++z){
          int m = m0 + z;
          rsp[tr * RSP_STRIDE + (m / 3) * 4 + (m % 3)] = vv[z];
        }
      }
    }
  }

  float4v acc[2][3];
  #pragma unroll
  for (int i = 0; i < 2; ++i)
    #pragma unroll
    for (int j = 0; j < 3; ++j) acc[i][j] = (float4v){0.f,0.f,0.f,0.f};

  __syncthreads();   // chunk-0 staged (drains vmcnt) + sL/rsp visible

  int swz = (lr & 7) << 4;
  #pragma unroll
  for (int cc = 0; cc < 8; ++cc){
    char* Ab = smem + ((cc & 1) ? AB1 : AB0);
    char* Bb = smem + ((cc & 1) ? BB1 : BB0);
    // issue next chunk's async stages into buf^1 (fly across the barrier; T4)
    if (cc < 7){
      int kc = (cc + 1) * 64;
      char* An = smem + ((cc & 1) ? AB0 : AB1);
      char* Bn = smem + ((cc & 1) ? BB0 : BB1);
      glds16(gA + kc, An + lA);
      glds16(gA + kc + 8 * F, An + lA + 1024);
      glds16(gB + kc, Bn + lB);
      if (w < 4) glds16(gB + kc + 8 * F, Bn + lB + 1024);
    }
    // wait ONLY the current chunk's loads (per-wave counted; next chunk stays in flight)
    if (cc < 7){
      if (w < 4) asm volatile("s_waitcnt vmcnt(4)" ::: "memory");
      else       asm volatile("s_waitcnt vmcnt(3)" ::: "memory");
    } else {
      asm volatile("s_waitcnt vmcnt(0)" ::: "memory");
    }
    asm volatile("s_barrier" ::: "memory");   // all waves' chunk-cc rows landed
    // compute chunk cc (swizzled fragment reads, 2-way banks = free)
    char* Ar = Ab + (wm * 32 + lr) * 128;
    char* Br = Bb + (wn * 48 + lr) * 128;
    #pragma unroll
    for (int ks = 0; ks < 2; ++ks){
      int ko = (ks * 64 + lg * 16) ^ swz;
      short8v a0 = *(const short8v*)(Ar + ko);
      short8v a1 = *(const short8v*)(Ar + 2048 + ko);
      short8v b0 = *(const short8v*)(Br + ko);
      short8v b1 = *(const short8v*)(Br + 2048 + ko);
      short8v b2 = *(const short8v*)(Br + 4096 + ko);
      acc[0][0] = __builtin_amdgcn_mfma_f32_16x16x32_bf16(a0, b0, acc[0][0], 0, 0, 0);
      acc[0][1] = __builtin_amdgcn_mfma_f32_16x16x32_bf16(a0, b1, acc[0][1], 0, 0, 0);
      acc[0][2] = __builtin_amdgcn_mfma_f32_16x16x32_bf16(a0, b2, acc[0][2], 0, 0, 0);
      acc[1][0] = __builtin_amdgcn_mfma_f32_16x16x32_bf16(a1, b0, acc[1][0], 0, 0, 0);
      acc[1][1] = __builtin_amdgcn_mfma_f32_16x16x32_bf16(a1, b1, acc[1][1], 0, 0, 0);
      acc[1][2] = __builtin_amdgcn_mfma_f32_16x16x32_bf16(a1, b2, acc[1][2], 0, 0, 0);
    }
    // readers done before next iter's glds overwrites this buffer
    asm volatile("s_barrier" ::: "memory");
  }

  // spill fv with 1/S scaling: C/D layout col=lane&15, row=(lane>>4)*4+reg
  float sf0 = sL[wn * 48 + lr];
  float sf1 = sL[wn * 48 + 16 + lr];
  float sf2 = sL[wn * 48 + 32 + lr];
  #pragma unroll
  for (int fm = 0; fm < 2; ++fm)
    #pragma unroll
    for (int r = 0; r < 4; ++r){
      int m = wm * 32 + fm * 16 + lg * 4 + r;
      fvl[m * 100 + wn * 48 + lr]      = acc[fm][0][r] * sf0;
      fvl[m * 100 + wn * 48 + 16 + lr] = acc[fm][1][r] * sf1;
      fvl[m * 100 + wn * 48 + 32 + lr] = acc[fm][2][r] * sf2;
    }
  __syncthreads();

  // ---- tree phase: thread owns tree tl for 4 rows bl0+32p ----
  int tl = t & 15, bl0 = t >> 4;     // bl0 in 0..31
  const float* thp = thr + (t0 + tl) * 6;
  const float* ltp = ltm + (t0 + tl) * 6;
  float av[DEPTH], cv[DEPTH];
  #pragma unroll
  for (int d = 0; d < DEPTH; ++d){
    av[d] = 0.5f * __expf(-ltp[d]);
    cv[d] = 0.5f - thp[d] * av[d];
  }
  float wv[4][16], qq[4][4];
  #pragma unroll
  for (int p = 0; p < 4; ++p){
    int bl = bl0 + 32 * p;
    float bn[DEPTH];
    #pragma unroll
    for (int d = 0; d < DEPTH; ++d)
      bn[d] = fminf(fmaxf(fvl[bl * 100 + tl * 6 + d] * av[d] + cv[d], 0.0f), 1.0f);
    wv[p][0] = bn[0]; wv[p][1] = 1.0f - bn[0];
    #pragma unroll
    for (int j = 1; j < 4; ++j){
      int half = 1 << j;
      float g = bn[j];
      #pragma unroll
      for (int i = 0; i < half; ++i){
        float o = wv[p][i];
        wv[p][i] = o * g;
        wv[p][i + half] = o - wv[p][i];   // o*(1-g)
      }
    }
    // quadrant multipliers: leaf = i + 16*bit4 + 32*bit5; bit set -> (1-bn)
    float p4 = bn[4], p5 = bn[5];
    qq[p][0] = p4 * p5;
    qq[p][1] = (1.0f - p4) * p5;
    qq[p][2] = p4 * (1.0f - p5);
    qq[p][3] = (1.0f - p4) * (1.0f - p5);
  }
  float4v oa[4];
  #pragma unroll
  for (int p = 0; p < 4; ++p) oa[p] = (float4v){0.f,0.f,0.f,0.f};
  const float* rp = rsp + tl * RSP_STRIDE;
  #pragma unroll
  for (int i = 0; i < 16; ++i){
    float4v r0  = *(const float4v*)(rp + i * 4);
    float4v r16 = *(const float4v*)(rp + (i + 16) * 4);
    float4v r32 = *(const float4v*)(rp + (i + 32) * 4);
    float4v r48 = *(const float4v*)(rp + (i + 48) * 4);
    #pragma unroll
    for (int p = 0; p < 4; ++p){
      float4v s = r0 * qq[p][0] + r16 * qq[p][1] + r32 * qq[p][2] + r48 * qq[p][3];
      oa[p] += s * wv[p][i];
    }
  }
  #pragma unroll
  for (int p = 0; p < 4; ++p){
    float* op = out + (b0 + bl0 + 32 * p) * (T * 3) + (t0 + tl) * 3;
    op[0] = oa[p][0]; op[1] = oa[p][1]; op[2] = oa[p][2];
  }
}

extern "C" void kernel_launch(void* const* d_in, const int* in_sizes, int n_in,
                              void* d_out, int out_size, void* d_ws, size_t ws_size,
                              hipStream_t stream){
  const float* x    = (const float*)d_in[0];
  const float* fa   = (const float*)d_in[1];
  const float* thr  = (const float*)d_in[2];
  const float* ltm  = (const float*)d_in[3];
  const float* resp = (const float*)d_in[4];
  float* out = (float*)d_out;

  unsigned short* cwT = (unsigned short*)d_ws;                      // @0, 3 MB
  unsigned short* xb  = (unsigned short*)((char*)d_ws + (3 << 20)); // @3MB, 1 MB
  float* partial      = (float*)((char*)d_ws + (4 << 20));          // @4MB, 192 KB

  k_prep<<<dim3(48, 16), 256, 0, stream>>>(fa, x, xb, cwT, partial);
  k_main<<<256, 512, 0, stream>>>(xb, cwT, thr, ltm, resp, partial, out);
}